// Round 10
// baseline (36.099 us; speedup 1.0000x reference)
//
#include <hip/hip_runtime.h>

// GSplat renderer, separable-Gaussian, LDS-resident, DS-instruction-minimized.
// R9 analysis: per-CU DS pipe bound (3 ds_reads/g/wave ~30cy -> 240cy/g/CU
// matches measured ~30us accum; VALU model predicts 12us -> not binding).
// Fix: ey(4 rows) + color(rgb,op) packed bf16 into ONE uint4 -> inner loop is
// 2 ds_reads per gaussian per wave (ex float2 + pack b128) ~19cy.
// Unpack = 8 shift/and. Dual-bank unroll-8, no rotation movs. ex stays f32.
// Geometry (R9): block = 64 cols x 32 rows, thread = 2 cols x 4 rows,
// NCHUNK=128, grid (4,8,16) = 512 blocks, parts=16 (partials 16 MB).

constexpr int HH = 256;
constexpr int WW = 256;
constexpr int PIX = HH * WW;
constexpr int NCHUNK = 128;
constexpr int PAD = 8;       // tail-prefetch landing zone (never computed)
constexpr int CPB = 64;
constexpr int RPB = 32;
constexpr float COORD_STEP = 2.0f / 255.0f;

__device__ __forceinline__ unsigned bfr(float f) {  // f32 -> bf16 bits (RNE)
  unsigned u = __float_as_uint(f);
  return (u + 0x7fffu + ((u >> 16) & 1u)) >> 16;
}

__global__ __launch_bounds__(256) void gs_accum(
    const float* __restrict__ means, const float* __restrict__ scales,
    const float* __restrict__ opac, const float* __restrict__ colors,
    float* __restrict__ partials) {
  __shared__ float pxL[NCHUNK], pyL[NCHUNK], kL[NCHUNK];
  __shared__ float4 colL[NCHUNK];
  __shared__ float exL[NCHUNK + PAD][CPB];   // 34.8 KB
  __shared__ uint4 packL[NCHUNK + PAD][8];   // 17.4 KB  [g][rowgroup]

  const int t = threadIdx.x;
  const int n0 = blockIdx.z * NCHUNK;

  // --- per-gaussian params ---
  if (t < NCHUNK) {
    int n = n0 + t;
    float mx = means[3 * n], my = means[3 * n + 1], mz = means[3 * n + 2];
    float scl = fmaxf((scales[3 * n] + scales[3 * n + 1] + scales[3 * n + 2]) * (1.0f / 3.0f), 1e-4f);
    float op = opac[n];
    float rzs = 1.0f / (fabsf(mz) + 1.0f);
    float sigma = fminf(fmaxf(scl * rzs, 0.02f), 0.5f);
    float inv_s = 1.0f / sigma;
    pxL[t] = tanhf(mx * rzs);
    pyL[t] = tanhf(my * rzs);
    kL[t] = -0.72134752044f * inv_s * inv_s;  // -0.5/ln2 * inv_s^2
    colL[t] = make_float4(op * colors[3 * n], op * colors[3 * n + 1],
                          op * colors[3 * n + 2], op);
  }
  __syncthreads();

  // --- tables into LDS (absolute coords) ---
  {
    int c = t & 63;
    int jb = t >> 6;  // 0..3
    float ccol = -1.0f + COORD_STEP * (float)(blockIdx.x * CPB + c);
#pragma unroll 8
    for (int jj = 0; jj < NCHUNK / 4; ++jj) {
      int j = jb + (jj << 2);
      float dx = ccol - pxL[j];
      exL[j][c] = exp2f(kL[j] * dx * dx);
    }
#pragma unroll
    for (int k = 0; k < 4; ++k) {   // 1024 pack entries / 256 threads
      int e = t + (k << 8);
      int j = e >> 3;       // gaussian 0..127
      int rgf = e & 7;      // rowgroup 0..7
      int rb = blockIdx.y * RPB + (rgf << 2);
      float py = pyL[j], K = kL[j];
      float d0 = (-1.0f + COORD_STEP * (float)(rb + 0)) - py;
      float d1 = (-1.0f + COORD_STEP * (float)(rb + 1)) - py;
      float d2 = (-1.0f + COORD_STEP * (float)(rb + 2)) - py;
      float d3 = (-1.0f + COORD_STEP * (float)(rb + 3)) - py;
      float e0 = exp2f(K * d0 * d0);
      float e1 = exp2f(K * d1 * d1);
      float e2 = exp2f(K * d2 * d2);
      float e3 = exp2f(K * d3 * d3);
      float4 cv = colL[j];
      packL[j][rgf] = make_uint4(bfr(e0) | (bfr(e1) << 16),
                                 bfr(e2) | (bfr(e3) << 16),
                                 bfr(cv.x) | (bfr(cv.y) << 16),
                                 bfr(cv.z) | (bfr(cv.w) << 16));
    }
  }
  __syncthreads();

  // --- main contraction: 2 ds_reads per gaussian per wave ---
  const int c0 = (t & 31) << 1;   // local col pair
  const int rg = t >> 5;          // rowgroup 0..7 (4 rows)

  float4 a00 = make_float4(0.f, 0.f, 0.f, 0.f);
  float4 a01 = a00, a10 = a00, a11 = a00, a20 = a00, a21 = a00,
         a30 = a00, a31 = a00;

#define DECL_BANK(S) float2 ex##S##0, ex##S##1, ex##S##2, ex##S##3; \
                     uint4 pk##S##0, pk##S##1, pk##S##2, pk##S##3;
#define LOAD_BANK(S, J)                               \
  ex##S##0 = *(const float2*)&exL[(J) + 0][c0];       \
  ex##S##1 = *(const float2*)&exL[(J) + 1][c0];       \
  ex##S##2 = *(const float2*)&exL[(J) + 2][c0];       \
  ex##S##3 = *(const float2*)&exL[(J) + 3][c0];       \
  pk##S##0 = packL[(J) + 0][rg];                      \
  pk##S##1 = packL[(J) + 1][rg];                      \
  pk##S##2 = packL[(J) + 2][rg];                      \
  pk##S##3 = packL[(J) + 3][rg];

#define GS_ROW(AR0, AR1, EY)                          \
  { float wA = (EY) * exv.x, wB = (EY) * exv.y;       \
    AR0.x = fmaf(wA, crr, AR0.x);                     \
    AR0.y = fmaf(wA, cgg, AR0.y);                     \
    AR0.z = fmaf(wA, cbb, AR0.z);                     \
    AR0.w = fmaf(wA, cop, AR0.w);                     \
    AR1.x = fmaf(wB, crr, AR1.x);                     \
    AR1.y = fmaf(wB, cgg, AR1.y);                     \
    AR1.z = fmaf(wB, cbb, AR1.z);                     \
    AR1.w = fmaf(wB, cop, AR1.w); }

#define COMP_G(EXV_, PKV_)                                   \
  { float2 exv = EXV_; uint4 pk = PKV_;                      \
    float ey0 = __uint_as_float(pk.x << 16);                 \
    float ey1 = __uint_as_float(pk.x & 0xffff0000u);         \
    float ey2 = __uint_as_float(pk.y << 16);                 \
    float ey3 = __uint_as_float(pk.y & 0xffff0000u);         \
    float crr = __uint_as_float(pk.z << 16);                 \
    float cgg = __uint_as_float(pk.z & 0xffff0000u);         \
    float cbb = __uint_as_float(pk.w << 16);                 \
    float cop = __uint_as_float(pk.w & 0xffff0000u);         \
    GS_ROW(a00, a01, ey0) GS_ROW(a10, a11, ey1)              \
    GS_ROW(a20, a21, ey2) GS_ROW(a30, a31, ey3) }

#define COMP_BANK(S)                                  \
  COMP_G(ex##S##0, pk##S##0) COMP_G(ex##S##1, pk##S##1) \
  COMP_G(ex##S##2, pk##S##2) COMP_G(ex##S##3, pk##S##3)

  DECL_BANK(A)
  DECL_BANK(B)
  LOAD_BANK(A, 0)
  LOAD_BANK(B, 4)
#pragma unroll 1
  for (int i = 0; i < NCHUNK; i += 8) {
    COMP_BANK(A)
    LOAD_BANK(A, i + 8)    // tail lands in PAD rows: loaded, never computed
    COMP_BANK(B)
    LOAD_BANK(B, i + 12)
  }
#undef DECL_BANK
#undef LOAD_BANK
#undef GS_ROW
#undef COMP_G
#undef COMP_BANK

  // --- epilogue ---
  float* pb = partials + (size_t)blockIdx.z * 4 * PIX;
  int colabs = blockIdx.x * CPB + c0;
  int rowb = blockIdx.y * RPB + (rg << 2);
#define GS_ST(A0, A1, R)                                     \
  { float* rowp = pb + (rowb + (R)) * WW + colabs;           \
    *(float2*)(rowp + 0 * PIX) = make_float2(A0.x, A1.x);    \
    *(float2*)(rowp + 1 * PIX) = make_float2(A0.y, A1.y);    \
    *(float2*)(rowp + 2 * PIX) = make_float2(A0.z, A1.z);    \
    *(float2*)(rowp + 3 * PIX) = make_float2(A0.w, A1.w); }
  GS_ST(a00, a01, 0)
  GS_ST(a10, a11, 1)
  GS_ST(a20, a21, 2)
  GS_ST(a30, a31, 3)
#undef GS_ST
}

// grid = PIX/4/256 = 64 blocks; thread = one 4-px group, all 4 planes.
__global__ __launch_bounds__(256) void gs_finalize(
    const float4* __restrict__ partials4, float4* __restrict__ out4,
    int parts) {
  int g = blockIdx.x * 256 + threadIdx.x;
  float4 sr = make_float4(0.f, 0.f, 0.f, 0.f);
  float4 sg = sr, sb = sr, sd = sr;
  const float4* p = partials4 + g;
#pragma unroll 4
  for (int part = 0; part < parts; ++part) {
    float4 a = p[0 * (PIX / 4)];
    float4 b = p[1 * (PIX / 4)];
    float4 c = p[2 * (PIX / 4)];
    float4 d = p[3 * (PIX / 4)];
    sr.x += a.x; sr.y += a.y; sr.z += a.z; sr.w += a.w;
    sg.x += b.x; sg.y += b.y; sg.z += b.z; sg.w += b.w;
    sb.x += c.x; sb.y += c.y; sb.z += c.z; sb.w += c.w;
    sd.x += d.x; sd.y += d.y; sd.z += d.z; sd.w += d.w;
    p += 4 * (PIX / 4);
  }
  float4 inv;
  inv.x = 1.0f / fmaxf(sd.x, 1e-5f);
  inv.y = 1.0f / fmaxf(sd.y, 1e-5f);
  inv.z = 1.0f / fmaxf(sd.z, 1e-5f);
  inv.w = 1.0f / fmaxf(sd.w, 1e-5f);
#define GS_FIN(S, CH)                                      \
  out4[(CH) * (PIX / 4) + g] = make_float4(                \
      fminf(fmaxf((S).x * inv.x, 0.0f), 1.0f),             \
      fminf(fmaxf((S).y * inv.y, 0.0f), 1.0f),             \
      fminf(fmaxf((S).z * inv.z, 0.0f), 1.0f),             \
      fminf(fmaxf((S).w * inv.w, 0.0f), 1.0f));
  GS_FIN(sr, 0)
  GS_FIN(sg, 1)
  GS_FIN(sb, 2)
#undef GS_FIN
}

extern "C" void kernel_launch(void* const* d_in, const int* in_sizes, int n_in,
                              void* d_out, int out_size, void* d_ws, size_t ws_size,
                              hipStream_t stream) {
  const float* means = (const float*)d_in[0];
  // d_in[1] = quats (unused by reference)
  const float* scales = (const float*)d_in[2];
  const float* opac = (const float*)d_in[3];
  const float* colors = (const float*)d_in[4];
  float* out = (float*)d_out;
  int N = in_sizes[0] / 3;  // 2048

  int parts = N / NCHUNK;  // 16
  float* partials = (float*)d_ws;  // [parts][4][PIX] float = 16 MB

  gs_accum<<<dim3(WW / CPB, HH / RPB, parts), 256, 0, stream>>>(
      means, scales, opac, colors, partials);
  gs_finalize<<<PIX / 4 / 256, 256, 0, stream>>>(
      (const float4*)partials, (float4*)out, parts);
}

// Round 11
// 34.871 us; speedup vs baseline: 1.0352x; 1.0352x over previous
//
#include <hip/hip_runtime.h>

// GSplat renderer, separable-Gaussian, LDS-resident accum + parallel reduce.
// R10 lesson: accum inner loop is at its ~11-13us issue floor (R7/R9/R10 all
// tie); the slack is in the reduction path. This round:
//  - partials are PIXEL-MAJOR float4 (r,g,b,denom) per pixel,
//  - finalize: 256 blocks, 1 px/thread, 16 independent b128 loads.
// Accum geometry: block = 64 cols x 32 rows, thread = 2 cols x 4 rows,
// NCHUNK=128, grid (4,8,16) = 512 blocks = 2/CU, LDS 51.5 KB.

constexpr int HH = 256;
constexpr int WW = 256;
constexpr int PIX = HH * WW;
constexpr int NCHUNK = 128;
constexpr int CPB = 64;
constexpr int RPB = 32;
constexpr float COORD_STEP = 2.0f / 255.0f;

__device__ __forceinline__ unsigned bfr(float f) {  // f32 -> bf16 bits (RNE)
  unsigned u = __float_as_uint(f);
  return (u + 0x7fffu + ((u >> 16) & 1u)) >> 16;
}

__global__ __launch_bounds__(256) void gs_accum(
    const float* __restrict__ means, const float* __restrict__ scales,
    const float* __restrict__ opac, const float* __restrict__ colors,
    float4* __restrict__ partials) {
  __shared__ float pxL[NCHUNK], pyL[NCHUNK], kL[NCHUNK];
  __shared__ float4 colL[NCHUNK];
  __shared__ float exL[NCHUNK][CPB];   // 32 KB
  __shared__ uint4 packL[NCHUNK][8];   // 16 KB  [g][rowgroup]

  const int t = threadIdx.x;
  const int n0 = blockIdx.z * NCHUNK;

  // --- per-gaussian params ---
  if (t < NCHUNK) {
    int n = n0 + t;
    float mx = means[3 * n], my = means[3 * n + 1], mz = means[3 * n + 2];
    float scl = fmaxf((scales[3 * n] + scales[3 * n + 1] + scales[3 * n + 2]) * (1.0f / 3.0f), 1e-4f);
    float op = opac[n];
    float rzs = 1.0f / (fabsf(mz) + 1.0f);
    float sigma = fminf(fmaxf(scl * rzs, 0.02f), 0.5f);
    float inv_s = 1.0f / sigma;
    pxL[t] = tanhf(mx * rzs);
    pyL[t] = tanhf(my * rzs);
    kL[t] = -0.72134752044f * inv_s * inv_s;  // -0.5/ln2 * inv_s^2
    colL[t] = make_float4(op * colors[3 * n], op * colors[3 * n + 1],
                          op * colors[3 * n + 2], op);
  }
  __syncthreads();

  // --- tables into LDS (absolute coords) ---
  {
    int c = t & 63;
    int jb = t >> 6;  // 0..3
    float ccol = -1.0f + COORD_STEP * (float)(blockIdx.x * CPB + c);
#pragma unroll 8
    for (int jj = 0; jj < NCHUNK / 4; ++jj) {
      int j = jb + (jj << 2);
      float dx = ccol - pxL[j];
      exL[j][c] = exp2f(kL[j] * dx * dx);
    }
#pragma unroll
    for (int k = 0; k < 4; ++k) {   // 1024 pack entries / 256 threads
      int e = t + (k << 8);
      int j = e >> 3;       // gaussian 0..127
      int rgf = e & 7;      // rowgroup 0..7
      int rb = blockIdx.y * RPB + (rgf << 2);
      float py = pyL[j], K = kL[j];
      float d0 = (-1.0f + COORD_STEP * (float)(rb + 0)) - py;
      float d1 = (-1.0f + COORD_STEP * (float)(rb + 1)) - py;
      float d2 = (-1.0f + COORD_STEP * (float)(rb + 2)) - py;
      float d3 = (-1.0f + COORD_STEP * (float)(rb + 3)) - py;
      float e0 = exp2f(K * d0 * d0);
      float e1 = exp2f(K * d1 * d1);
      float e2 = exp2f(K * d2 * d2);
      float e3 = exp2f(K * d3 * d3);
      float4 cv = colL[j];
      packL[j][rgf] = make_uint4(bfr(e0) | (bfr(e1) << 16),
                                 bfr(e2) | (bfr(e3) << 16),
                                 bfr(cv.x) | (bfr(cv.y) << 16),
                                 bfr(cv.z) | (bfr(cv.w) << 16));
    }
  }
  __syncthreads();

  // --- main contraction: 2 ds_reads per gaussian per wave ---
  const int c0 = (t & 31) << 1;   // local col pair
  const int rg = t >> 5;          // rowgroup 0..7 (4 rows)

  float4 a00 = make_float4(0.f, 0.f, 0.f, 0.f);
  float4 a01 = a00, a10 = a00, a11 = a00, a20 = a00, a21 = a00,
         a30 = a00, a31 = a00;

#pragma unroll 4
  for (int i = 0; i < NCHUNK; ++i) {
    float2 exv = *(const float2*)&exL[i][c0];
    uint4 pk = packL[i][rg];
    float ey0 = __uint_as_float(pk.x << 16);
    float ey1 = __uint_as_float(pk.x & 0xffff0000u);
    float ey2 = __uint_as_float(pk.y << 16);
    float ey3 = __uint_as_float(pk.y & 0xffff0000u);
    float crr = __uint_as_float(pk.z << 16);
    float cgg = __uint_as_float(pk.z & 0xffff0000u);
    float cbb = __uint_as_float(pk.w << 16);
    float cop = __uint_as_float(pk.w & 0xffff0000u);
#define GS_ROW(AR0, AR1, EY)                          \
    { float wA = (EY) * exv.x, wB = (EY) * exv.y;     \
      AR0.x = fmaf(wA, crr, AR0.x);                   \
      AR0.y = fmaf(wA, cgg, AR0.y);                   \
      AR0.z = fmaf(wA, cbb, AR0.z);                   \
      AR0.w = fmaf(wA, cop, AR0.w);                   \
      AR1.x = fmaf(wB, crr, AR1.x);                   \
      AR1.y = fmaf(wB, cgg, AR1.y);                   \
      AR1.z = fmaf(wB, cbb, AR1.z);                   \
      AR1.w = fmaf(wB, cop, AR1.w); }
    GS_ROW(a00, a01, ey0)
    GS_ROW(a10, a11, ey1)
    GS_ROW(a20, a21, ey2)
    GS_ROW(a30, a31, ey3)
#undef GS_ROW
  }

  // --- epilogue: pixel-major float4 (r,g,b,denom) ---
  float4* pb = partials + (size_t)blockIdx.z * PIX;
  int colabs = blockIdx.x * CPB + c0;
  int rowb = blockIdx.y * RPB + (rg << 2);
#define GS_ST(A0, A1, R)                              \
  { float4* rowp = pb + (rowb + (R)) * WW + colabs;   \
    rowp[0] = A0;                                     \
    rowp[1] = A1; }
  GS_ST(a00, a01, 0)
  GS_ST(a10, a11, 1)
  GS_ST(a20, a21, 2)
  GS_ST(a30, a31, 3)
#undef GS_ST
}

// grid = PIX/256 = 256 blocks; thread = one pixel; 16 independent b128 loads.
__global__ __launch_bounds__(256) void gs_finalize(
    const float4* __restrict__ partials, float* __restrict__ out,
    int parts) {
  int g = blockIdx.x * 256 + threadIdx.x;  // pixel id
  float sr = 0.f, sg = 0.f, sb = 0.f, sd = 0.f;
#pragma unroll 16
  for (int p = 0; p < parts; ++p) {
    float4 v = partials[(size_t)p * PIX + g];
    sr += v.x; sg += v.y; sb += v.z; sd += v.w;
  }
  float inv = 1.0f / fmaxf(sd, 1e-5f);
  out[0 * PIX + g] = fminf(fmaxf(sr * inv, 0.0f), 1.0f);
  out[1 * PIX + g] = fminf(fmaxf(sg * inv, 0.0f), 1.0f);
  out[2 * PIX + g] = fminf(fmaxf(sb * inv, 0.0f), 1.0f);
}

extern "C" void kernel_launch(void* const* d_in, const int* in_sizes, int n_in,
                              void* d_out, int out_size, void* d_ws, size_t ws_size,
                              hipStream_t stream) {
  const float* means = (const float*)d_in[0];
  // d_in[1] = quats (unused by reference)
  const float* scales = (const float*)d_in[2];
  const float* opac = (const float*)d_in[3];
  const float* colors = (const float*)d_in[4];
  float* out = (float*)d_out;
  int N = in_sizes[0] / 3;  // 2048

  int parts = N / NCHUNK;  // 16
  float4* partials = (float4*)d_ws;  // [parts][PIX] float4 = 16 MB

  gs_accum<<<dim3(WW / CPB, HH / RPB, parts), 256, 0, stream>>>(
      means, scales, opac, colors, partials);
  gs_finalize<<<PIX / 256, 256, 0, stream>>>(
      partials, out, parts);
}